// Round 1
// baseline (184.104 us; speedup 1.0000x reference)
//
#include <hip/hip_runtime.h>
#include <math.h>

#define N_SEG 4096
#define FEAT 64
#define WINDOW 3

// ---------------------------------------------------------------------------
// Kernel 1: exclusive prefix sum of sizes[4096] -> starts[4096] (in d_ws).
// Single block of 64 threads; each thread serially sums 64 elements, wave
// shfl-scan of the 64 partials, then serial write-out. ~microseconds.
// ---------------------------------------------------------------------------
__global__ __launch_bounds__(64) void dmax_scan_kernel(
    const int* __restrict__ sizes, int* __restrict__ starts) {
  const int t = threadIdx.x;            // 0..63
  const int per = N_SEG / 64;           // 64
  const int base = t * per;

  int s = 0;
#pragma unroll 4
  for (int i = 0; i < per; ++i) s += sizes[base + i];

  // inclusive scan across the wave
  int v = s;
#pragma unroll
  for (int d = 1; d < 64; d <<= 1) {
    int o = __shfl_up(v, d, 64);
    if (t >= d) v += o;
  }
  int run = v - s;  // exclusive prefix for this thread's chunk

  for (int i = 0; i < per; ++i) {
    starts[base + i] = run;
    run += sizes[base + i];
  }
}

// ---------------------------------------------------------------------------
// Kernel 2: one block per segment. 256 threads:
//   chunk   = t & 15  -> which float4 of the 64-float feature row
//   rowslot = t >> 4  -> row phase (16 rows in flight per iteration)
// Running float4 max in registers over rows [start, start+cnt), then
// shfl_xor(16,32) within-wave + LDS across the 4 waves.
// ---------------------------------------------------------------------------
__global__ __launch_bounds__(256) void dmax_segmax_kernel(
    const float* __restrict__ in, const int* __restrict__ sizes,
    const int* __restrict__ starts, float* __restrict__ out) {
  const int seg = blockIdx.x;
  const int start = starts[seg];
  const int cnt = sizes[seg] - (WINDOW - 1);  // valid rows, >= 1 by construction

  const int t = threadIdx.x;
  const int chunk = t & 15;
  const int rowslot = t >> 4;  // 0..15

  const float* base = in + (size_t)start * FEAT + chunk * 4;

  float4 m = make_float4(-INFINITY, -INFINITY, -INFINITY, -INFINITY);
  for (int r = rowslot; r < cnt; r += 16) {
    const float4 v = *reinterpret_cast<const float4*>(base + (size_t)r * FEAT);
    m.x = fmaxf(m.x, v.x);
    m.y = fmaxf(m.y, v.y);
    m.z = fmaxf(m.z, v.z);
    m.w = fmaxf(m.w, v.w);
  }

  // Reduce the 4 rowslots within each wave (lane bits 4 and 5).
#pragma unroll
  for (int mask = 16; mask <= 32; mask <<= 1) {
    m.x = fmaxf(m.x, __shfl_xor(m.x, mask, 64));
    m.y = fmaxf(m.y, __shfl_xor(m.y, mask, 64));
    m.z = fmaxf(m.z, __shfl_xor(m.z, mask, 64));
    m.w = fmaxf(m.w, __shfl_xor(m.w, mask, 64));
  }

  // Cross-wave reduce via LDS: each wave's lanes 0..15 hold the wave max.
  __shared__ float red[4][FEAT];
  const int wave = t >> 6;
  const int lane = t & 63;
  if (lane < 16) {
    red[wave][chunk * 4 + 0] = m.x;
    red[wave][chunk * 4 + 1] = m.y;
    red[wave][chunk * 4 + 2] = m.z;
    red[wave][chunk * 4 + 3] = m.w;
  }
  __syncthreads();

  if (t < FEAT) {
    float v = fmaxf(fmaxf(red[0][t], red[1][t]), fmaxf(red[2][t], red[3][t]));
    out[(size_t)seg * FEAT + t] = v;
  }
}

extern "C" void kernel_launch(void* const* d_in, const int* in_sizes, int n_in,
                              void* d_out, int out_size, void* d_ws, size_t ws_size,
                              hipStream_t stream) {
  const float* input = (const float*)d_in[0];
  const int* sizes = (const int*)d_in[1];
  float* out = (float*)d_out;
  int* starts = (int*)d_ws;  // 4096 ints = 16 KB scratch

  dmax_scan_kernel<<<1, 64, 0, stream>>>(sizes, starts);
  dmax_segmax_kernel<<<N_SEG, 256, 0, stream>>>(input, sizes, starts, out);
}

// Round 2
// 112.076 us; speedup vs baseline: 1.6427x; 1.6427x over previous
//
#include <hip/hip_runtime.h>
#include <math.h>

#define TOTAL 2097152
#define N_SEG 4096
#define FEAT 64
#define WINDOW 3
#define ROWS_PER_BLOCK 512
#define N_CHUNK (TOTAL / ROWS_PER_BLOCK)  // 4096

// Monotone order-preserving float<->uint32 key (no NaNs in input).
__device__ __forceinline__ unsigned fkey(float f) {
  unsigned b = __float_as_uint(f);
  return (b & 0x80000000u) ? ~b : (b | 0x80000000u);
}
__device__ __forceinline__ float fdec(unsigned k) {
  unsigned b = (k & 0x80000000u) ? (k & 0x7FFFFFFFu) : ~k;
  return __uint_as_float(b);
}

// ---------------------------------------------------------------------------
// Kernel 1: exclusive prefix sum of sizes[4096] -> starts[4096] (in d_ws).
// ---------------------------------------------------------------------------
__global__ __launch_bounds__(64) void dmax_scan_kernel(
    const int* __restrict__ sizes, int* __restrict__ starts) {
  const int t = threadIdx.x;  // 0..63
  const int per = N_SEG / 64; // 64
  const int base = t * per;

  int s = 0;
#pragma unroll 4
  for (int i = 0; i < per; ++i) s += sizes[base + i];

  int v = s;
#pragma unroll
  for (int d = 1; d < 64; d <<= 1) {
    int o = __shfl_up(v, d, 64);
    if (t >= d) v += o;
  }
  int run = v - s;

  for (int i = 0; i < per; ++i) {
    starts[base + i] = run;
    run += sizes[base + i];
  }
}

// ---------------------------------------------------------------------------
// Kernel 2: zero-init the key buffer (every segment has >=1 valid row, and
// all keys are > 0, so 0 is a safe identity).
// ---------------------------------------------------------------------------
__global__ __launch_bounds__(256) void dmax_init_kernel(unsigned* __restrict__ outk) {
  const int i = blockIdx.x * 256 + threadIdx.x;  // 256 blocks * 256 thr = 64K uint4
  reinterpret_cast<uint4*>(outk)[i] = make_uint4(0u, 0u, 0u, 0u);
}

// ---------------------------------------------------------------------------
// Kernel 3: balanced chunk kernel. One block per 512 contiguous rows.
//   chunk   = t & 15  -> which float4 of the 64-float feature row
//   rowslot = t >> 4  -> row phase (16 rows in flight)
// Walk the segments overlapping this chunk; register-reduce each sub-range,
// then atomicMax 64 keys into the output.
// ---------------------------------------------------------------------------
__global__ __launch_bounds__(256) void dmax_chunk_kernel(
    const float* __restrict__ in, const int* __restrict__ sizes,
    const int* __restrict__ starts, unsigned* __restrict__ outk) {
  const int chunk_lo = blockIdx.x * ROWS_PER_BLOCK;
  const int chunk_hi = chunk_lo + ROWS_PER_BLOCK;  // TOTAL divisible

  const int t = threadIdx.x;
  const int fchunk = t & 15;
  const int rowslot = t >> 4;
  const int wave = t >> 6;

  // Binary search: largest seg with starts[seg] <= chunk_lo.
  int lo = 0, hi = N_SEG - 1;
  while (lo < hi) {
    int mid = (lo + hi + 1) >> 1;
    if (starts[mid] <= chunk_lo) lo = mid; else hi = mid - 1;
  }
  int seg = lo;

  __shared__ float red[4][FEAT];
  const float* basep = in + fchunk * 4;

  int row = chunk_lo;
  while (row < chunk_hi) {
    const int s_start = starts[seg];
    const int s_size = sizes[seg];
    const int s_vend = s_start + s_size - (WINDOW - 1);  // valid end
    const int s_end = s_start + s_size;

    const int rlo = row;
    const int rhi = min(chunk_hi, s_vend);

    if (rhi > rlo) {
      float4 m = make_float4(-INFINITY, -INFINITY, -INFINITY, -INFINITY);
#pragma unroll 4
      for (int r = rlo + rowslot; r < rhi; r += 16) {
        const float4 v =
            *reinterpret_cast<const float4*>(basep + (size_t)r * FEAT);
        m.x = fmaxf(m.x, v.x);
        m.y = fmaxf(m.y, v.y);
        m.z = fmaxf(m.z, v.z);
        m.w = fmaxf(m.w, v.w);
      }
      // reduce rowslots within wave (t bits 4,5)
#pragma unroll
      for (int mask = 16; mask <= 32; mask <<= 1) {
        m.x = fmaxf(m.x, __shfl_xor(m.x, mask, 64));
        m.y = fmaxf(m.y, __shfl_xor(m.y, mask, 64));
        m.z = fmaxf(m.z, __shfl_xor(m.z, mask, 64));
        m.w = fmaxf(m.w, __shfl_xor(m.w, mask, 64));
      }
      __syncthreads();  // protect red[] from previous iteration's readers
      if ((t & 63) < 16) {
        red[wave][fchunk * 4 + 0] = m.x;
        red[wave][fchunk * 4 + 1] = m.y;
        red[wave][fchunk * 4 + 2] = m.z;
        red[wave][fchunk * 4 + 3] = m.w;
      }
      __syncthreads();
      if (t < FEAT) {
        float v = fmaxf(fmaxf(red[0][t], red[1][t]),
                        fmaxf(red[2][t], red[3][t]));
        atomicMax(outk + (size_t)seg * FEAT + t, fkey(v));
      }
    }

    row = min(chunk_hi, s_end);
    ++seg;
  }
}

// ---------------------------------------------------------------------------
// Kernel 4: decode keys -> floats in place.
// ---------------------------------------------------------------------------
__global__ __launch_bounds__(256) void dmax_decode_kernel(unsigned* __restrict__ outk) {
  const int i = blockIdx.x * 256 + threadIdx.x;  // 256 blocks: 64K uint4
  uint4 k = reinterpret_cast<uint4*>(outk)[i];
  float4 f = make_float4(fdec(k.x), fdec(k.y), fdec(k.z), fdec(k.w));
  reinterpret_cast<float4*>(outk)[i] = f;
}

extern "C" void kernel_launch(void* const* d_in, const int* in_sizes, int n_in,
                              void* d_out, int out_size, void* d_ws, size_t ws_size,
                              hipStream_t stream) {
  const float* input = (const float*)d_in[0];
  const int* sizes = (const int*)d_in[1];
  unsigned* outk = (unsigned*)d_out;  // used as key buffer, decoded in place
  int* starts = (int*)d_ws;           // 16 KB scratch

  dmax_scan_kernel<<<1, 64, 0, stream>>>(sizes, starts);
  dmax_init_kernel<<<(N_SEG * FEAT / 4) / 256, 256, 0, stream>>>(outk);
  dmax_chunk_kernel<<<N_CHUNK, 256, 0, stream>>>(input, sizes, starts, outk);
  dmax_decode_kernel<<<(N_SEG * FEAT / 4) / 256, 256, 0, stream>>>(outk);
}